// Round 9
// baseline (544.196 us; speedup 1.0000x reference)
//
#include <hip/hip_runtime.h>
#include <hip/hip_bf16.h>
#include <cstddef>

// Problem constants
#define BATCH 32
#define TSTEPS 20
#define IN_DIM 3
#define WIDTH 256
#define HID 64
#define FC1_IN 327680   // HID * TSTEPS * WIDTH
#define FC1_OUT 512
#define OUT_DIM 3

typedef _Float16 half8 __attribute__((ext_vector_type(8)));
typedef float floatx4 __attribute__((ext_vector_type(4)));

__device__ __forceinline__ float sigm(float x) {
    return 1.0f / (1.0f + __expf(-x));
}
__device__ __forceinline__ float tanh_fast(float x) {
    return 1.0f - 2.0f / (__expf(2.0f * x) + 1.0f);
}

// ---------------- prep kernels (once per launch) ----------------

// wt0[kw][co][cip=96]: NEW slot order: cip 0..63 = h ch (orig ci 3+cip),
// cip 64..66 = x ch (orig ci cip-64), 67..95 = 0.  (kh=1 slice only.)
__global__ __launch_bounds__(256) void prep_w0(
    const float* __restrict__ cw0, _Float16* __restrict__ wt0)
{
    int e = blockIdx.x * 256 + threadIdx.x;   // < 256*96
    if (e >= 256 * 96) return;
    int co = e / 96, cip = e - co * 96;
    int ci = (cip < 64) ? (3 + cip) : (cip < 67 ? cip - 64 : -1);
    float v[3] = {0.f, 0.f, 0.f};
    if (ci >= 0) {
#pragma unroll
        for (int kw = 0; kw < 3; ++kw)
            v[kw] = cw0[(size_t)(co * 67 + ci) * 9 + 3 + kw];
    }
#pragma unroll
    for (int kw = 0; kw < 3; ++kw)
        wt0[(size_t)(kw * 256 + co) * 96 + cip] = (_Float16)v[kw];
}

// wt1[kw][co][ci=128]: direct (z = [h0 64 | h1 64] matches cw1 ci order).
__global__ __launch_bounds__(256) void prep_w1(
    const float* __restrict__ cw1, _Float16* __restrict__ wt1)
{
    int e = blockIdx.x * 256 + threadIdx.x;   // < 256*128
    int co = e >> 7, ci = e & 127;
#pragma unroll
    for (int kw = 0; kw < 3; ++kw)
        wt1[(size_t)(kw * 256 + co) * 128 + ci] =
            (_Float16)cw1[(size_t)(co * 128 + ci) * 9 + 3 + kw];
}

// xT[t][b][w][8] fp16: ch 0..2 from x[b][t][ch][w], 3..7 = 0.
__global__ __launch_bounds__(256) void prep_x(
    const float* __restrict__ x, _Float16* __restrict__ xT)
{
    int e = blockIdx.x * 256 + threadIdx.x;   // < 20*32*256
    if (e >= TSTEPS * BATCH * WIDTH) return;
    int t = e / (BATCH * WIDTH);
    int rem = e - t * BATCH * WIDTH;
    int b = rem >> 8, w = rem & 255;
    half8 v = {};
#pragma unroll
    for (int ci = 0; ci < 3; ++ci)
        v[ci] = (_Float16)x[(size_t)((b * TSTEPS + t) * IN_DIM + ci) * WIDTH + w];
    *(half8*)&xT[(size_t)e * 8] = v;
}

// ---------------- whole-sequence ConvLSTM kernel (halo-grow, zero comm) ----
// Grid (32 b, 8 wtiles), 512 threads = 8 waves; waves 0-3 = layer0, 4-7 = layer1.
// Each block computes a FIXED 80-col region w in [w0-24, w0+56); boundary error
// propagates <=1 col/layer/step => after 20 steps <=20 cols contaminated, core
// [w0, w0+32) stays exact (margin 24). True domain edges (w<0, w>=256) enforced
// by skipping h-writes there (h slab stays zero = real zero-pad).
// 21-phase pipeline, 1 barrier/phase: phase p runs L0(t=p) || L1(t=p-1).
// State: h0/h1 double-buffered LDS (XOR-swizzled 16B chunks), c0 in LDS
// (bank-swizzled), c1 in registers, weights register-resident (loaded once).
__global__ __launch_bounds__(512) void conv_seq(
    const _Float16* __restrict__ xT,   // [t][b][w][8]
    const _Float16* __restrict__ wt0,  // [3][256][96]  (reordered slots)
    const _Float16* __restrict__ wt1,  // [3][256][128]
    const float* __restrict__ cb0,
    const float* __restrict__ cb1,
    _Float16* __restrict__ fcin)       // [b][(t*64+hc)*256+w] fp16
{
    // slab row s <-> w = w0-25+s, s = 0..81. 8 chunks of 16B/row; logical
    // chunk c stored at physical c ^ (row&7) (bank-conflict-free ds_read_b128).
    __shared__ __align__(16) _Float16 h0s[2][82 * 64];
    __shared__ __align__(16) _Float16 h1s[2][82 * 64];
    __shared__ __align__(16) _Float16 xs[2][82 * 8];   // 16B/row, no swizzle
    __shared__ float c0s[80 * 64];                     // idx n*64 + (hc ^ (kg<<4))
    __shared__ __align__(16) _Float16 zero16[8];

    const int b    = blockIdx.x;
    const int w0   = blockIdx.y * 32;
    const int tid  = threadIdx.x;
    const int wave = tid >> 6;
    const int ln = tid & 63;
    const int lr = ln & 15;
    const int kg = ln >> 4;

    // ---- zero-init LDS + stage x(0)
    {
        _Float16* h0f = &h0s[0][0];
        _Float16* h1f = &h1s[0][0];
        for (int i = tid; i < 2 * 82 * 64; i += 512) { h0f[i] = (_Float16)0.0f; h1f[i] = (_Float16)0.0f; }
        for (int i = tid; i < 80 * 64; i += 512) c0s[i] = 0.0f;
        for (int i = tid; i < 82 * 8; i += 512) xs[1][i] = (_Float16)0.0f;
        if (tid < 8) zero16[tid] = (_Float16)0.0f;
        if (tid < 82) {
            int w = w0 - 25 + tid;
            half8 v = {};
            if (w >= 0 && w < WIDTH)
                v = *(const half8*)&xT[((size_t)(0 * BATCH + b) * WIDTH + w) * 8];
            *(half8*)&xs[0][tid * 8] = v;
        }
    }

    if (wave < 4) {
        // ================= LAYER-0 WAVES =================
        const int hc = wave * 16 + lr;

        half8 b0r[3][3][4];
#pragma unroll
        for (int kw = 0; kw < 3; ++kw)
#pragma unroll
        for (int kf = 0; kf < 3; ++kf)
#pragma unroll
        for (int cf = 0; cf < 4; ++cf)
            b0r[kw][kf][cf] = *(const half8*)&wt0[
                (size_t)(kw * 256 + cf * 64 + hc) * 96 + kf * 32 + kg * 8];

        float cbr0[4];
#pragma unroll
        for (int cf = 0; cf < 4; ++cf) cbr0[cf] = cb0[cf * 64 + hc];

        __syncthreads();   // init barrier

        for (int p = 0; p < 21; ++p) {
            const int rd = (p ^ 1) & 1;   // h0(p-1)
            const int wr = p & 1;         // h0(p) dest; also xs[p&1] = x(p)
            half8 xreg = {};
            const bool xst = (p < 19) && (tid < 82);
            if (xst) {
                int w = w0 - 25 + tid;
                if (w >= 0 && w < WIDTH)
                    xreg = *(const half8*)&xT[((size_t)((p + 1) * BATCH + b) * WIDTH + w) * 8];
            }
            if (p < 20) {
#pragma unroll
                for (int j = 0; j < 5; ++j) {
                    floatx4 acc[4];
#pragma unroll
                    for (int cf = 0; cf < 4; ++cf) acc[cf] = (floatx4)0.0f;
#pragma unroll
                    for (int kw = 0; kw < 3; ++kw)
#pragma unroll
                    for (int kf = 0; kf < 3; ++kf) {
                        int row = 16 * j + lr + kw;     // 0..81
                        half8 a;
                        if (kf < 2) {
                            int phys = (kf * 4 + kg) ^ (row & 7);
                            a = *(const half8*)&h0s[rd][row * 64 + phys * 8];
                        } else {
                            a = (kg == 0) ? *(const half8*)&xs[wr][row * 8]
                                          : *(const half8*)&zero16[0];
                        }
#pragma unroll
                        for (int cf = 0; cf < 4; ++cf)
                            acc[cf] = __builtin_amdgcn_mfma_f32_16x16x32_f16(a, b0r[kw][kf][cf], acc[cf], 0, 0, 0);
                    }
                    // register-local epilogue: thread owns (n = 16j+kg*4+r, hc)
#pragma unroll
                    for (int r = 0; r < 4; ++r) {
                        int n = 16 * j + kg * 4 + r;
                        int cidx = n * 64 + (hc ^ (kg << 4));
                        float cv = c0s[cidx];
                        float cn = sigm(acc[1][r] + cbr0[1]) * cv
                                 + sigm(acc[0][r] + cbr0[0]) * tanh_fast(acc[3][r] + cbr0[3]);
                        c0s[cidx] = cn;
                        int w = w0 - 24 + n;
                        if (w >= 0 && w < WIDTH) {   // true zero-pad at domain edge
                            _Float16 hv = (_Float16)(sigm(acc[2][r] + cbr0[2]) * tanh_fast(cn));
                            int rowo = n + 1;
                            int phys = (hc >> 3) ^ (rowo & 7);
                            *((_Float16*)((char*)&h0s[wr][0] + rowo * 128 + phys * 16 + (hc & 7) * 2)) = hv;
                        }
                    }
                }
            }
            if (xst) *(half8*)&xs[(p + 1) & 1][tid * 8] = xreg;
            __syncthreads();
        }
    } else {
        // ================= LAYER-1 WAVES =================
        const int hc = (wave - 4) * 16 + lr;

        half8 b1r[3][4][4];
#pragma unroll
        for (int kw = 0; kw < 3; ++kw)
#pragma unroll
        for (int kf = 0; kf < 4; ++kf)
#pragma unroll
        for (int cf = 0; cf < 4; ++cf)
            b1r[kw][kf][cf] = *(const half8*)&wt1[
                (size_t)(kw * 256 + cf * 64 + hc) * 128 + kf * 32 + kg * 8];

        float cbr1[4];
#pragma unroll
        for (int cf = 0; cf < 4; ++cf) cbr1[cf] = cb1[cf * 64 + hc];

        float c1r[5][4];
#pragma unroll
        for (int j = 0; j < 5; ++j)
#pragma unroll
            for (int r = 0; r < 4; ++r) c1r[j][r] = 0.0f;

        __syncthreads();   // init barrier

        for (int p = 0; p < 21; ++p) {
            const int rd   = (p ^ 1) & 1;  // h0(p-1) read; h1(p-1) write
            const int h1rd = p & 1;        // h1(p-2) read
            if (p >= 1) {
#pragma unroll
                for (int j = 0; j < 5; ++j) {
                    floatx4 acc[4];
#pragma unroll
                    for (int cf = 0; cf < 4; ++cf) acc[cf] = (floatx4)0.0f;
#pragma unroll
                    for (int kw = 0; kw < 3; ++kw)
#pragma unroll
                    for (int kf = 0; kf < 4; ++kf) {
                        int row = 16 * j + lr + kw;
                        half8 a;
                        if (kf < 2) {
                            int phys = (kf * 4 + kg) ^ (row & 7);
                            a = *(const half8*)&h0s[rd][row * 64 + phys * 8];
                        } else {
                            int phys = ((kf - 2) * 4 + kg) ^ (row & 7);
                            a = *(const half8*)&h1s[h1rd][row * 64 + phys * 8];
                        }
#pragma unroll
                        for (int cf = 0; cf < 4; ++cf)
                            acc[cf] = __builtin_amdgcn_mfma_f32_16x16x32_f16(a, b1r[kw][kf][cf], acc[cf], 0, 0, 0);
                    }
#pragma unroll
                    for (int r = 0; r < 4; ++r) {
                        int n = 16 * j + kg * 4 + r;
                        float cv = c1r[j][r];
                        float cn = sigm(acc[1][r] + cbr1[1]) * cv
                                 + sigm(acc[0][r] + cbr1[0]) * tanh_fast(acc[3][r] + cbr1[3]);
                        c1r[j][r] = cn;
                        _Float16 hv = (_Float16)(sigm(acc[2][r] + cbr1[2]) * tanh_fast(cn));
                        int w = w0 - 24 + n;
                        if (w >= 0 && w < WIDTH) {
                            int rowo = n + 1;
                            int phys = (hc >> 3) ^ (rowo & 7);
                            *((_Float16*)((char*)&h1s[rd][0] + rowo * 128 + phys * 16 + (hc & 7) * 2)) = hv;
                        }
                        if (n >= 24 && n < 56)   // core: w in [w0, w0+32)
                            fcin[(size_t)b * FC1_IN + (size_t)((p - 1) * HID + hc) * WIDTH + w] = hv;
                    }
                }
            }
            __syncthreads();
        }
    }
}

// ---------------- FC1 fp16 MFMA GEMM, K-split (512 slices of 640) ----------
#define KSLICE 640
#define NSPLIT 512
#define ALDS_STRIDE 648

__global__ __launch_bounds__(512) void fc1_mfma(
    const _Float16* __restrict__ a,   // fcin [32][327680] fp16
    const float* __restrict__ w,      // fc1_w [512][327680] fp32
    float* __restrict__ part)         // [512][512][32] fp32 partials
{
    __shared__ _Float16 alds[32][ALDS_STRIDE];

    const int blk = blockIdx.x;
    const int tid = threadIdx.x;
    const int wv  = tid >> 6;
    const int ln  = tid & 63;
    const int lg  = ln >> 4;
    const int lr  = ln & 15;
    const int k0  = blk * KSLICE;

    floatx4 acc[2][4];
#pragma unroll
    for (int bt = 0; bt < 2; ++bt)
#pragma unroll
        for (int nt = 0; nt < 4; ++nt) acc[bt][nt] = (floatx4)0.0f;

    const float* wbase[4];
#pragma unroll
    for (int nt = 0; nt < 4; ++nt)
        wbase[nt] = w + (size_t)(wv * 64 + nt * 16 + lr) * FC1_IN + k0 + lg * 8;

    // stage a[32][k0..k0+640) as half8: 2560 vectors / 512 threads
    for (int i = tid; i < 32 * 80; i += 512) {
        int r = i / 80;
        int c = (i - r * 80) * 8;
        *(half8*)&alds[r][c] = *(const half8*)&a[(size_t)r * FC1_IN + k0 + c];
    }
    __syncthreads();

    for (int kc = 0; kc < KSLICE / 32; ++kc) {
        half8 af0 = *(const half8*)&alds[lr][kc * 32 + lg * 8];
        half8 af1 = *(const half8*)&alds[16 + lr][kc * 32 + lg * 8];
#pragma unroll
        for (int nt = 0; nt < 4; ++nt) {
            const float* wp = wbase[nt] + kc * 32;
            float4 wlo = *(const float4*)wp;
            float4 whi = *(const float4*)(wp + 4);
            half8 bf;
            bf[0] = (_Float16)wlo.x; bf[1] = (_Float16)wlo.y;
            bf[2] = (_Float16)wlo.z; bf[3] = (_Float16)wlo.w;
            bf[4] = (_Float16)whi.x; bf[5] = (_Float16)whi.y;
            bf[6] = (_Float16)whi.z; bf[7] = (_Float16)whi.w;
            acc[0][nt] = __builtin_amdgcn_mfma_f32_16x16x32_f16(af0, bf, acc[0][nt], 0, 0, 0);
            acc[1][nt] = __builtin_amdgcn_mfma_f32_16x16x32_f16(af1, bf, acc[1][nt], 0, 0, 0);
        }
    }

#pragma unroll
    for (int bt = 0; bt < 2; ++bt)
#pragma unroll
        for (int nt = 0; nt < 4; ++nt) {
            int n = wv * 64 + nt * 16 + lr;
            int b = bt * 16 + lg * 4;
            *(float4*)&part[((size_t)blk * FC1_OUT + n) * BATCH + b] =
                *(float4*)&acc[bt][nt];
        }
}

__global__ __launch_bounds__(256) void fc1_reduce(
    const float* __restrict__ part, const float* __restrict__ b1,
    float* __restrict__ z1)
{
    int e = blockIdx.x * 256 + threadIdx.x;  // e = n*32 + b
    float s = 0.0f;
    for (int ks = 0; ks < NSPLIT; ++ks)
        s += part[(size_t)ks * (FC1_OUT * BATCH) + e];
    int n = e >> 5, b = e & 31;
    float v = s + b1[n];
    z1[(size_t)b * FC1_OUT + n] = v > 0.0f ? v : 0.0f;
}

__global__ __launch_bounds__(128) void fc2_kernel(
    const float* __restrict__ z1, const float* __restrict__ w2,
    const float* __restrict__ b2, float* __restrict__ out)
{
    int t = threadIdx.x;
    if (t >= BATCH * OUT_DIM) return;
    int b = t / OUT_DIM, n = t - b * OUT_DIM;
    const float* zr = z1 + (size_t)b * FC1_OUT;
    const float* wr = w2 + (size_t)n * FC1_OUT;
    float acc = b2[n];
    for (int k = 0; k < FC1_OUT; ++k) acc += zr[k] * wr[k];
    if (n == 2) acc = sigm(acc);
    out[(size_t)b * OUT_DIM + n] = acc;
}

extern "C" void kernel_launch(void* const* d_in, const int* in_sizes, int n_in,
                              void* d_out, int out_size, void* d_ws, size_t ws_size,
                              hipStream_t stream) {
    const float* x   = (const float*)d_in[0];
    const float* cw0 = (const float*)d_in[1];
    const float* cb0 = (const float*)d_in[2];
    const float* cw1 = (const float*)d_in[3];
    const float* cb1 = (const float*)d_in[4];
    const float* w1  = (const float*)d_in[5];
    const float* b1  = (const float*)d_in[6];
    const float* w2  = (const float*)d_in[7];
    const float* b2  = (const float*)d_in[8];
    float* out = (float*)d_out;

    char* p = (char*)d_ws;
    auto alloc = [&](size_t bytes) { char* r = p; p += (bytes + 255) & ~(size_t)255; return r; };

    _Float16* wt0  = (_Float16*)alloc((size_t)3 * 256 * 96 * 2);
    _Float16* wt1  = (_Float16*)alloc((size_t)3 * 256 * 128 * 2);
    _Float16* xT   = (_Float16*)alloc((size_t)TSTEPS * BATCH * WIDTH * 8 * 2);
    _Float16* fcin = (_Float16*)alloc((size_t)BATCH * FC1_IN * 2);
    float*    part = (float*)alloc((size_t)NSPLIT * FC1_OUT * BATCH * 4);
    float*    z1   = (float*)alloc((size_t)BATCH * FC1_OUT * 4);

    prep_w0<<<96, 256, 0, stream>>>(cw0, wt0);
    prep_w1<<<128, 256, 0, stream>>>(cw1, wt1);
    prep_x<<<(TSTEPS * BATCH * WIDTH + 255) / 256, 256, 0, stream>>>(x, xT);

    conv_seq<<<dim3(BATCH, 8), 512, 0, stream>>>(xT, wt0, wt1, cb0, cb1, fcin);

    fc1_mfma<<<NSPLIT, 512, 0, stream>>>(fcin, w1, part);
    fc1_reduce<<<64, 256, 0, stream>>>(part, b1, z1);
    fc2_kernel<<<1, 128, 0, stream>>>(z1, w2, b2, out);
}

// Round 10
// 517.013 us; speedup vs baseline: 1.0526x; 1.0526x over previous
//
#include <hip/hip_runtime.h>
#include <hip/hip_bf16.h>
#include <cstddef>

// Problem constants
#define BATCH 32
#define TSTEPS 20
#define IN_DIM 3
#define WIDTH 256
#define HID 64
#define FC1_IN 327680   // HID * TSTEPS * WIDTH
#define FC1_OUT 512
#define OUT_DIM 3

typedef _Float16 half8 __attribute__((ext_vector_type(8)));
typedef float floatx4 __attribute__((ext_vector_type(4)));

__device__ __forceinline__ float sigm(float x) {
    return 1.0f / (1.0f + __expf(-x));
}
__device__ __forceinline__ float tanh_fast(float x) {
    return 1.0f - 2.0f / (__expf(2.0f * x) + 1.0f);
}

// ---------------- prep kernels (once per launch) ----------------

// wt0[kw][co][cip=96]: cip 0..63 = h ch (orig ci 3+cip), 64..66 = x ch, 67..95 = 0.
__global__ __launch_bounds__(256) void prep_w0(
    const float* __restrict__ cw0, _Float16* __restrict__ wt0)
{
    int e = blockIdx.x * 256 + threadIdx.x;   // < 256*96
    if (e >= 256 * 96) return;
    int co = e / 96, cip = e - co * 96;
    int ci = (cip < 64) ? (3 + cip) : (cip < 67 ? cip - 64 : -1);
    float v[3] = {0.f, 0.f, 0.f};
    if (ci >= 0) {
#pragma unroll
        for (int kw = 0; kw < 3; ++kw)
            v[kw] = cw0[(size_t)(co * 67 + ci) * 9 + 3 + kw];
    }
#pragma unroll
    for (int kw = 0; kw < 3; ++kw)
        wt0[(size_t)(kw * 256 + co) * 96 + cip] = (_Float16)v[kw];
}

// wt1[kw][co][ci=128]: direct (z = [h0 64 | h1 64] matches cw1 ci order).
__global__ __launch_bounds__(256) void prep_w1(
    const float* __restrict__ cw1, _Float16* __restrict__ wt1)
{
    int e = blockIdx.x * 256 + threadIdx.x;   // < 256*128
    int co = e >> 7, ci = e & 127;
#pragma unroll
    for (int kw = 0; kw < 3; ++kw)
        wt1[(size_t)(kw * 256 + co) * 128 + ci] =
            (_Float16)cw1[(size_t)(co * 128 + ci) * 9 + 3 + kw];
}

// xT[t][b][w][8] fp16: ch 0..2 from x[b][t][ch][w], 3..7 = 0.
__global__ __launch_bounds__(256) void prep_x(
    const float* __restrict__ x, _Float16* __restrict__ xT)
{
    int e = blockIdx.x * 256 + threadIdx.x;   // < 20*32*256
    if (e >= TSTEPS * BATCH * WIDTH) return;
    int t = e / (BATCH * WIDTH);
    int rem = e - t * BATCH * WIDTH;
    int b = rem >> 8, w = rem & 255;
    half8 v = {};
#pragma unroll
    for (int ci = 0; ci < 3; ++ci)
        v[ci] = (_Float16)x[(size_t)((b * TSTEPS + t) * IN_DIM + ci) * WIDTH + w];
    *(half8*)&xT[(size_t)e * 8] = v;
}

// ---------------- whole-sequence ConvLSTM kernel (halo-grow, zero comm) ----
// Grid (32 b, 8 wtiles), 512 threads = 8 waves; waves 0-3 = layer0, 4-7 = layer1.
// Each block computes a FIXED 80-col region w in [w0-24, w0+56); boundary error
// propagates (B_h1(t) = w0-24+t+1), so core [w0, w0+32) stays exact for t<=19.
// True domain edges enforced by skipping h-writes (h slab stays zero).
// 21-phase pipeline, 1 barrier/phase: phase p runs L0(t=p) || L1(t=p-1).
// State: h0/h1 double-buffered LDS (XOR-swizzled), c0 AND c1 in LDS
// (bank-swizzled, thread-owned RMW), weights register-resident (loaded once).
// Register budget: L0 ~195, L1 ~230 VGPR -> no scratch spill (round-9 fix:
// c1 moved from 20 regs to LDS; r9 was at ~260 -> spilled).
__global__ __launch_bounds__(512) void conv_seq(
    const _Float16* __restrict__ xT,   // [t][b][w][8]
    const _Float16* __restrict__ wt0,  // [3][256][96]  (reordered slots)
    const _Float16* __restrict__ wt1,  // [3][256][128]
    const float* __restrict__ cb0,
    const float* __restrict__ cb1,
    _Float16* __restrict__ fcin)       // [b][(t*64+hc)*256+w] fp16
{
    // slab row s <-> w = w0-25+s, s = 0..81. 8 chunks of 16B/row; logical
    // chunk c stored at physical c ^ (row&7) (bank-conflict-free ds_read_b128).
    __shared__ __align__(16) _Float16 h0s[2][82 * 64];
    __shared__ __align__(16) _Float16 h1s[2][82 * 64];
    __shared__ __align__(16) _Float16 xs[2][82 * 8];   // 16B/row, no swizzle
    __shared__ float c0s[80 * 64];                     // idx n*64 + (hc ^ (kg<<4))
    __shared__ float c1s[80 * 64];                     // same swizzle
    __shared__ __align__(16) _Float16 zero16[8];

    const int b    = blockIdx.x;
    const int w0   = blockIdx.y * 32;
    const int tid  = threadIdx.x;
    const int wave = tid >> 6;
    const int ln = tid & 63;
    const int lr = ln & 15;
    const int kg = ln >> 4;

    // ---- zero-init LDS + stage x(0)
    {
        _Float16* h0f = &h0s[0][0];
        _Float16* h1f = &h1s[0][0];
        for (int i = tid; i < 2 * 82 * 64; i += 512) { h0f[i] = (_Float16)0.0f; h1f[i] = (_Float16)0.0f; }
        for (int i = tid; i < 80 * 64; i += 512) { c0s[i] = 0.0f; c1s[i] = 0.0f; }
        for (int i = tid; i < 82 * 8; i += 512) xs[1][i] = (_Float16)0.0f;
        if (tid < 8) zero16[tid] = (_Float16)0.0f;
        if (tid < 82) {
            int w = w0 - 25 + tid;
            half8 v = {};
            if (w >= 0 && w < WIDTH)
                v = *(const half8*)&xT[((size_t)(0 * BATCH + b) * WIDTH + w) * 8];
            *(half8*)&xs[0][tid * 8] = v;
        }
    }

    if (wave < 4) {
        // ================= LAYER-0 WAVES =================
        const int hc = wave * 16 + lr;

        half8 b0r[3][3][4];
#pragma unroll
        for (int kw = 0; kw < 3; ++kw)
#pragma unroll
        for (int kf = 0; kf < 3; ++kf)
#pragma unroll
        for (int cf = 0; cf < 4; ++cf)
            b0r[kw][kf][cf] = *(const half8*)&wt0[
                (size_t)(kw * 256 + cf * 64 + hc) * 96 + kf * 32 + kg * 8];

        float cbr0[4];
#pragma unroll
        for (int cf = 0; cf < 4; ++cf) cbr0[cf] = cb0[cf * 64 + hc];

        __syncthreads();   // init barrier

        for (int p = 0; p < 21; ++p) {
            const int rd = (p ^ 1) & 1;   // h0(p-1)
            const int wr = p & 1;         // h0(p) dest; also xs[p&1] = x(p)
            half8 xreg = {};
            const bool xst = (p < 19) && (tid < 82);
            if (xst) {
                int w = w0 - 25 + tid;
                if (w >= 0 && w < WIDTH)
                    xreg = *(const half8*)&xT[((size_t)((p + 1) * BATCH + b) * WIDTH + w) * 8];
            }
            if (p < 20) {
#pragma unroll
                for (int j = 0; j < 5; ++j) {
                    floatx4 acc[4];
#pragma unroll
                    for (int cf = 0; cf < 4; ++cf) acc[cf] = (floatx4)0.0f;
#pragma unroll
                    for (int kw = 0; kw < 3; ++kw)
#pragma unroll
                    for (int kf = 0; kf < 3; ++kf) {
                        int row = 16 * j + lr + kw;     // 0..81
                        half8 a;
                        if (kf < 2) {
                            int phys = (kf * 4 + kg) ^ (row & 7);
                            a = *(const half8*)&h0s[rd][row * 64 + phys * 8];
                        } else {
                            a = (kg == 0) ? *(const half8*)&xs[wr][row * 8]
                                          : *(const half8*)&zero16[0];
                        }
#pragma unroll
                        for (int cf = 0; cf < 4; ++cf)
                            acc[cf] = __builtin_amdgcn_mfma_f32_16x16x32_f16(a, b0r[kw][kf][cf], acc[cf], 0, 0, 0);
                    }
                    // register-local epilogue: thread owns (n = 16j+kg*4+r, hc)
#pragma unroll
                    for (int r = 0; r < 4; ++r) {
                        int n = 16 * j + kg * 4 + r;
                        int cidx = n * 64 + (hc ^ (kg << 4));
                        float cv = c0s[cidx];
                        float cn = sigm(acc[1][r] + cbr0[1]) * cv
                                 + sigm(acc[0][r] + cbr0[0]) * tanh_fast(acc[3][r] + cbr0[3]);
                        c0s[cidx] = cn;
                        int w = w0 - 24 + n;
                        if (w >= 0 && w < WIDTH) {   // true zero-pad at domain edge
                            _Float16 hv = (_Float16)(sigm(acc[2][r] + cbr0[2]) * tanh_fast(cn));
                            int rowo = n + 1;
                            int phys = (hc >> 3) ^ (rowo & 7);
                            *((_Float16*)((char*)&h0s[wr][0] + rowo * 128 + phys * 16 + (hc & 7) * 2)) = hv;
                        }
                    }
                }
            }
            if (xst) *(half8*)&xs[(p + 1) & 1][tid * 8] = xreg;
            __syncthreads();
        }
    } else {
        // ================= LAYER-1 WAVES =================
        const int hc = (wave - 4) * 16 + lr;

        half8 b1r[3][4][4];
#pragma unroll
        for (int kw = 0; kw < 3; ++kw)
#pragma unroll
        for (int kf = 0; kf < 4; ++kf)
#pragma unroll
        for (int cf = 0; cf < 4; ++cf)
            b1r[kw][kf][cf] = *(const half8*)&wt1[
                (size_t)(kw * 256 + cf * 64 + hc) * 128 + kf * 32 + kg * 8];

        float cbr1[4];
#pragma unroll
        for (int cf = 0; cf < 4; ++cf) cbr1[cf] = cb1[cf * 64 + hc];

        __syncthreads();   // init barrier

        for (int p = 0; p < 21; ++p) {
            const int rd   = (p ^ 1) & 1;  // h0(p-1) read; h1(p-1) write
            const int h1rd = p & 1;        // h1(p-2) read
            if (p >= 1) {
#pragma unroll
                for (int j = 0; j < 5; ++j) {
                    floatx4 acc[4];
#pragma unroll
                    for (int cf = 0; cf < 4; ++cf) acc[cf] = (floatx4)0.0f;
#pragma unroll
                    for (int kw = 0; kw < 3; ++kw)
#pragma unroll
                    for (int kf = 0; kf < 4; ++kf) {
                        int row = 16 * j + lr + kw;
                        half8 a;
                        if (kf < 2) {
                            int phys = (kf * 4 + kg) ^ (row & 7);
                            a = *(const half8*)&h0s[rd][row * 64 + phys * 8];
                        } else {
                            int phys = ((kf - 2) * 4 + kg) ^ (row & 7);
                            a = *(const half8*)&h1s[h1rd][row * 64 + phys * 8];
                        }
#pragma unroll
                        for (int cf = 0; cf < 4; ++cf)
                            acc[cf] = __builtin_amdgcn_mfma_f32_16x16x32_f16(a, b1r[kw][kf][cf], acc[cf], 0, 0, 0);
                    }
#pragma unroll
                    for (int r = 0; r < 4; ++r) {
                        int n = 16 * j + kg * 4 + r;
                        int cidx = n * 64 + (hc ^ (kg << 4));
                        float cv = c1s[cidx];
                        float cn = sigm(acc[1][r] + cbr1[1]) * cv
                                 + sigm(acc[0][r] + cbr1[0]) * tanh_fast(acc[3][r] + cbr1[3]);
                        c1s[cidx] = cn;
                        _Float16 hv = (_Float16)(sigm(acc[2][r] + cbr1[2]) * tanh_fast(cn));
                        int w = w0 - 24 + n;
                        if (w >= 0 && w < WIDTH) {
                            int rowo = n + 1;
                            int phys = (hc >> 3) ^ (rowo & 7);
                            *((_Float16*)((char*)&h1s[rd][0] + rowo * 128 + phys * 16 + (hc & 7) * 2)) = hv;
                        }
                        if (n >= 24 && n < 56)   // core: w in [w0, w0+32)
                            fcin[(size_t)b * FC1_IN + (size_t)((p - 1) * HID + hc) * WIDTH + w] = hv;
                    }
                }
            }
            __syncthreads();
        }
    }
}

// ---------------- FC1 fp16 MFMA GEMM, K-split (round-8 proven config) ------
#define KSLICE 1280
#define KPHASE 640
#define NSPLIT 256
#define ALDS_STRIDE 648

__global__ __launch_bounds__(512) void fc1_mfma(
    const _Float16* __restrict__ a,   // fcin [32][327680] fp16
    const float* __restrict__ w,      // fc1_w [512][327680] fp32
    float* __restrict__ part)         // [256][512][32] fp32 partials
{
    __shared__ _Float16 alds[32][ALDS_STRIDE];

    const int blk = blockIdx.x;
    const int tid = threadIdx.x;
    const int wv  = tid >> 6;
    const int ln  = tid & 63;
    const int lg  = ln >> 4;
    const int lr  = ln & 15;
    const int k0  = blk * KSLICE;

    floatx4 acc[2][4];
#pragma unroll
    for (int bt = 0; bt < 2; ++bt)
#pragma unroll
        for (int nt = 0; nt < 4; ++nt) acc[bt][nt] = (floatx4)0.0f;

    const float* wbase[4];
#pragma unroll
    for (int nt = 0; nt < 4; ++nt)
        wbase[nt] = w + (size_t)(wv * 64 + nt * 16 + lr) * FC1_IN + k0 + lg * 8;

    for (int p = 0; p < 2; ++p) {
        __syncthreads();
        for (int i = tid; i < 32 * 80; i += 512) {
            int r = i / 80;
            int c = (i - r * 80) * 8;
            *(half8*)&alds[r][c] =
                *(const half8*)&a[(size_t)r * FC1_IN + k0 + p * KPHASE + c];
        }
        __syncthreads();

        for (int kc = 0; kc < KPHASE / 32; ++kc) {
            half8 af0 = *(const half8*)&alds[lr][kc * 32 + lg * 8];
            half8 af1 = *(const half8*)&alds[16 + lr][kc * 32 + lg * 8];
#pragma unroll
            for (int nt = 0; nt < 4; ++nt) {
                const float* wp = wbase[nt] + p * KPHASE + kc * 32;
                float4 wlo = *(const float4*)wp;
                float4 whi = *(const float4*)(wp + 4);
                half8 bf;
                bf[0] = (_Float16)wlo.x; bf[1] = (_Float16)wlo.y;
                bf[2] = (_Float16)wlo.z; bf[3] = (_Float16)wlo.w;
                bf[4] = (_Float16)whi.x; bf[5] = (_Float16)whi.y;
                bf[6] = (_Float16)whi.z; bf[7] = (_Float16)whi.w;
                acc[0][nt] = __builtin_amdgcn_mfma_f32_16x16x32_f16(af0, bf, acc[0][nt], 0, 0, 0);
                acc[1][nt] = __builtin_amdgcn_mfma_f32_16x16x32_f16(af1, bf, acc[1][nt], 0, 0, 0);
            }
        }
    }

#pragma unroll
    for (int bt = 0; bt < 2; ++bt)
#pragma unroll
        for (int nt = 0; nt < 4; ++nt) {
            int n = wv * 64 + nt * 16 + lr;
            int b = bt * 16 + lg * 4;
            *(float4*)&part[((size_t)blk * FC1_OUT + n) * BATCH + b] =
                *(float4*)&acc[bt][nt];
        }
}

__global__ __launch_bounds__(256) void fc1_reduce(
    const float* __restrict__ part, const float* __restrict__ b1,
    float* __restrict__ z1)
{
    int e = blockIdx.x * 256 + threadIdx.x;  // e = n*32 + b
    float s = 0.0f;
    for (int ks = 0; ks < NSPLIT; ++ks)
        s += part[(size_t)ks * (FC1_OUT * BATCH) + e];
    int n = e >> 5, b = e & 31;
    float v = s + b1[n];
    z1[(size_t)b * FC1_OUT + n] = v > 0.0f ? v : 0.0f;
}

__global__ __launch_bounds__(128) void fc2_kernel(
    const float* __restrict__ z1, const float* __restrict__ w2,
    const float* __restrict__ b2, float* __restrict__ out)
{
    int t = threadIdx.x;
    if (t >= BATCH * OUT_DIM) return;
    int b = t / OUT_DIM, n = t - b * OUT_DIM;
    const float* zr = z1 + (size_t)b * FC1_OUT;
    const float* wr = w2 + (size_t)n * FC1_OUT;
    float acc = b2[n];
    for (int k = 0; k < FC1_OUT; ++k) acc += zr[k] * wr[k];
    if (n == 2) acc = sigm(acc);
    out[(size_t)b * OUT_DIM + n] = acc;
}

extern "C" void kernel_launch(void* const* d_in, const int* in_sizes, int n_in,
                              void* d_out, int out_size, void* d_ws, size_t ws_size,
                              hipStream_t stream) {
    const float* x   = (const float*)d_in[0];
    const float* cw0 = (const float*)d_in[1];
    const float* cb0 = (const float*)d_in[2];
    const float* cw1 = (const float*)d_in[3];
    const float* cb1 = (const float*)d_in[4];
    const float* w1  = (const float*)d_in[5];
    const float* b1  = (const float*)d_in[6];
    const float* w2  = (const float*)d_in[7];
    const float* b2  = (const float*)d_in[8];
    float* out = (float*)d_out;

    char* p = (char*)d_ws;
    auto alloc = [&](size_t bytes) { char* r = p; p += (bytes + 255) & ~(size_t)255; return r; };

    _Float16* wt0  = (_Float16*)alloc((size_t)3 * 256 * 96 * 2);
    _Float16* wt1  = (_Float16*)alloc((size_t)3 * 256 * 128 * 2);
    _Float16* xT   = (_Float16*)alloc((size_t)TSTEPS * BATCH * WIDTH * 8 * 2);
    _Float16* fcin = (_Float16*)alloc((size_t)BATCH * FC1_IN * 2);
    float*    part = (float*)alloc((size_t)NSPLIT * FC1_OUT * BATCH * 4);
    float*    z1   = (float*)alloc((size_t)BATCH * FC1_OUT * 4);

    prep_w0<<<96, 256, 0, stream>>>(cw0, wt0);
    prep_w1<<<128, 256, 0, stream>>>(cw1, wt1);
    prep_x<<<(TSTEPS * BATCH * WIDTH + 255) / 256, 256, 0, stream>>>(x, xT);

    conv_seq<<<dim3(BATCH, 8), 512, 0, stream>>>(xT, wt0, wt1, cb0, cb1, fcin);

    fc1_mfma<<<NSPLIT, 512, 0, stream>>>(fcin, w1, part);
    fc1_reduce<<<64, 256, 0, stream>>>(part, b1, z1);
    fc2_kernel<<<1, 128, 0, stream>>>(z1, w2, b2, out);
}

// Round 11
// 435.085 us; speedup vs baseline: 1.2508x; 1.1883x over previous
//
#include <hip/hip_runtime.h>
#include <hip/hip_bf16.h>
#include <cstddef>

// Problem constants
#define BATCH 32
#define TSTEPS 20
#define IN_DIM 3
#define WIDTH 256
#define HID 64
#define FC1_IN 327680   // HID * TSTEPS * WIDTH
#define FC1_OUT 512
#define OUT_DIM 3

// Conv time-chunking geometry
#define CST 5     // steps per chunk (4 chunks)
#define MARG 6    // halo margin >= CST+1
#define REGC 44   // region cols computed per block (32 core + 2*MARG)
#define CORE 6    // core starts at n=CORE
#define ROWS 50   // LDS slab rows (region rows 1..44, junk-absorb 45..48, zero 49)
#define CROWS 48  // c-state rows (junk rows 44..47 absorbed)

typedef _Float16 half8 __attribute__((ext_vector_type(8)));
typedef float floatx4 __attribute__((ext_vector_type(4)));

__device__ __forceinline__ float sigm(float x) {
    return 1.0f / (1.0f + __expf(-x));
}
__device__ __forceinline__ float tanh_fast(float x) {
    return 1.0f - 2.0f / (__expf(2.0f * x) + 1.0f);
}

// ---------------- prep kernels (once per launch) ----------------

// wt0[kw][co][cip=96]: cip 0..63 = h ch (orig ci 3+cip), 64..66 = x ch, 67..95 = 0.
__global__ __launch_bounds__(256) void prep_w0(
    const float* __restrict__ cw0, _Float16* __restrict__ wt0)
{
    int e = blockIdx.x * 256 + threadIdx.x;   // < 256*96
    if (e >= 256 * 96) return;
    int co = e / 96, cip = e - co * 96;
    int ci = (cip < 64) ? (3 + cip) : (cip < 67 ? cip - 64 : -1);
    float v[3] = {0.f, 0.f, 0.f};
    if (ci >= 0) {
#pragma unroll
        for (int kw = 0; kw < 3; ++kw)
            v[kw] = cw0[(size_t)(co * 67 + ci) * 9 + 3 + kw];
    }
#pragma unroll
    for (int kw = 0; kw < 3; ++kw)
        wt0[(size_t)(kw * 256 + co) * 96 + cip] = (_Float16)v[kw];
}

// wt1[kw][co][ci=128]: direct (z = [h0 64 | h1 64] matches cw1 ci order).
__global__ __launch_bounds__(256) void prep_w1(
    const float* __restrict__ cw1, _Float16* __restrict__ wt1)
{
    int e = blockIdx.x * 256 + threadIdx.x;   // < 256*128
    int co = e >> 7, ci = e & 127;
#pragma unroll
    for (int kw = 0; kw < 3; ++kw)
        wt1[(size_t)(kw * 256 + co) * 128 + ci] =
            (_Float16)cw1[(size_t)(co * 128 + ci) * 9 + 3 + kw];
}

// xT[t][b][w][8] fp16: ch 0..2 from x[b][t][ch][w], 3..7 = 0.
__global__ __launch_bounds__(256) void prep_x(
    const float* __restrict__ x, _Float16* __restrict__ xT)
{
    int e = blockIdx.x * 256 + threadIdx.x;   // < 20*32*256
    if (e >= TSTEPS * BATCH * WIDTH) return;
    int t = e / (BATCH * WIDTH);
    int rem = e - t * BATCH * WIDTH;
    int b = rem >> 8, w = rem & 255;
    half8 v = {};
#pragma unroll
    for (int ci = 0; ci < 3; ++ci)
        v[ci] = (_Float16)x[(size_t)((b * TSTEPS + t) * IN_DIM + ci) * WIDTH + w];
    *(half8*)&xT[(size_t)e * 8] = v;
}

// ---------------- time-chunked ConvLSTM kernel (5 steps/launch) ----------
// Grid (32 b, 8 wtiles), 512 threads = 8 waves; waves 0-3 = layer0, 4-7 = layer1.
// Per chunk each block computes region w in [w0-6, w0+38) (44 cols); boundary
// contamination grows 1 col/layer/step, margin 6 >= 5+1 keeps core [w0,w0+32)
// exact. Kernel boundary = exact halo exchange: chunk end stores CORE state to
// global; chunk start loads the full region (neighbors' cores cover margins).
// Row s <-> w = w0-7+s. 6 phases/chunk: phase p runs L0(t0+p) || L1(t0+p-1).
// Weights register-resident; h0/h1 double-buffered LDS; c0/c1 LDS.
__global__ __launch_bounds__(512) void conv_chunk(
    const _Float16* __restrict__ xT,   // [t][b][w][8]
    const _Float16* __restrict__ wt0,  // [3][256][96]  (reordered slots)
    const _Float16* __restrict__ wt1,  // [3][256][128]
    const float* __restrict__ cb0,
    const float* __restrict__ cb1,
    _Float16* __restrict__ fcin,       // [b][(t*64+hc)*256+w] fp16
    _Float16* __restrict__ h0g,        // [b][w][64] state between chunks
    _Float16* __restrict__ h1g,
    float* __restrict__ c0g,
    float* __restrict__ c1g,
    int t0, int first, int save)
{
    // 64 halves (128B)/row; 8 chunks of 16B; logical chunk c at phys c^(row&7)
    __shared__ __align__(16) _Float16 h0s[2][ROWS * 64];
    __shared__ __align__(16) _Float16 h1s[2][ROWS * 64];
    __shared__ __align__(16) _Float16 xs[2][ROWS * 8];
    __shared__ float c0s[CROWS * 64];   // idx n*64 + (hc ^ (owner_kg<<4))
    __shared__ float c1s[CROWS * 64];
    __shared__ __align__(16) _Float16 zero16[8];

    const int b    = blockIdx.x;
    const int w0   = blockIdx.y * 32;
    const int tid  = threadIdx.x;
    const int wave = tid >> 6;
    const int ln = tid & 63;
    const int lr = ln & 15;
    const int kg = ln >> 4;

    // ---- zero-init LDS
    {
        _Float16* h0f = &h0s[0][0];
        _Float16* h1f = &h1s[0][0];
        for (int i = tid; i < 2 * ROWS * 64; i += 512) { h0f[i] = (_Float16)0.0f; h1f[i] = (_Float16)0.0f; }
        for (int i = tid; i < CROWS * 64; i += 512) { c0s[i] = 0.0f; c1s[i] = 0.0f; }
        for (int i = tid; i < ROWS * 8; i += 512) xs[1][i] = (_Float16)0.0f;
        if (tid < 8) zero16[tid] = (_Float16)0.0f;
    }
    __syncthreads();

    // ---- stage x(t0) + load chunk-start state (races with zeroing avoided)
    {
        if (tid < ROWS) {
            int w = w0 - 7 + tid;
            half8 v = {};
            if (w >= 0 && w < WIDTH)
                v = *(const half8*)&xT[((size_t)(t0 * BATCH + b) * WIDTH + w) * 8];
            *(half8*)&xs[0][tid * 8] = v;
        }
        if (!first) {
            // h state -> buffers [1] (read at p=0/p=1), rows 1..44
            for (int i = tid; i < REGC * 8; i += 512) {
                int row = 1 + (i >> 3), c = i & 7;
                int w = w0 - 7 + row;
                half8 v0 = {}, v1 = {};
                if (w >= 0 && w < WIDTH) {
                    v0 = *(const half8*)&h0g[((size_t)b * WIDTH + w) * 64 + c * 8];
                    v1 = *(const half8*)&h1g[((size_t)b * WIDTH + w) * 64 + c * 8];
                }
                int phys = c ^ (row & 7);
                *(half8*)&h0s[1][row * 64 + phys * 8] = v0;
                *(half8*)&h1s[1][row * 64 + phys * 8] = v1;
            }
            for (int i = tid; i < REGC * 64; i += 512) {
                int n = i >> 6, hc = i & 63;
                int w = w0 - 6 + n;
                float v0 = 0.f, v1 = 0.f;
                if (w >= 0 && w < WIDTH) {
                    v0 = c0g[((size_t)b * WIDTH + w) * 64 + hc];
                    v1 = c1g[((size_t)b * WIDTH + w) * 64 + hc];
                }
                int ci = n * 64 + (hc ^ (((n >> 2) & 3) << 4));
                c0s[ci] = v0;
                c1s[ci] = v1;
            }
        }
    }

    if (wave < 4) {
        // ================= LAYER-0 WAVES =================
        const int hc = wave * 16 + lr;

        half8 b0r[3][3][4];
#pragma unroll
        for (int kw = 0; kw < 3; ++kw)
#pragma unroll
        for (int kf = 0; kf < 3; ++kf)
#pragma unroll
        for (int cf = 0; cf < 4; ++cf)
            b0r[kw][kf][cf] = *(const half8*)&wt0[
                (size_t)(kw * 256 + cf * 64 + hc) * 96 + kf * 32 + kg * 8];

        float cbr0[4];
#pragma unroll
        for (int cf = 0; cf < 4; ++cf) cbr0[cf] = cb0[cf * 64 + hc];

        __syncthreads();   // init barrier

        for (int p = 0; p <= CST; ++p) {
            const int rd = (p ^ 1) & 1;   // h0(t0+p-1)
            const int wr = p & 1;         // h0(t0+p) dest; xs[p&1] = x(t0+p)
            half8 xreg = {};
            const bool xst = (p < CST - 1) && (tid < ROWS);
            if (xst) {
                int w = w0 - 7 + tid;
                if (w >= 0 && w < WIDTH)
                    xreg = *(const half8*)&xT[((size_t)((t0 + p + 1) * BATCH + b) * WIDTH + w) * 8];
            }
            if (p < CST) {
#pragma unroll
                for (int j = 0; j < 3; ++j) {
                    floatx4 acc[4];
#pragma unroll
                    for (int cf = 0; cf < 4; ++cf) acc[cf] = (floatx4)0.0f;
#pragma unroll
                    for (int kw = 0; kw < 3; ++kw)
#pragma unroll
                    for (int kf = 0; kf < 3; ++kf) {
                        int row = 16 * j + lr + kw;     // <= 49
                        half8 a;
                        if (kf < 2) {
                            int phys = (kf * 4 + kg) ^ (row & 7);
                            a = *(const half8*)&h0s[rd][row * 64 + phys * 8];
                        } else {
                            a = (kg == 0) ? *(const half8*)&xs[wr][row * 8]
                                          : *(const half8*)&zero16[0];
                        }
#pragma unroll
                        for (int cf = 0; cf < 4; ++cf)
                            acc[cf] = __builtin_amdgcn_mfma_f32_16x16x32_f16(a, b0r[kw][kf][cf], acc[cf], 0, 0, 0);
                    }
#pragma unroll
                    for (int r = 0; r < 4; ++r) {
                        int n = 16 * j + kg * 4 + r;   // 0..47 (44..47 junk, absorbed)
                        int cidx = n * 64 + (hc ^ (kg << 4));
                        float cv = c0s[cidx];
                        float cn = sigm(acc[1][r] + cbr0[1]) * cv
                                 + sigm(acc[0][r] + cbr0[0]) * tanh_fast(acc[3][r] + cbr0[3]);
                        c0s[cidx] = cn;
                        int w = w0 - 6 + n;
                        if (w >= 0 && w < WIDTH) {   // domain zero-pad preserved
                            _Float16 hv = (_Float16)(sigm(acc[2][r] + cbr0[2]) * tanh_fast(cn));
                            int rowo = n + 1;        // <= 48 < ROWS
                            int phys = (hc >> 3) ^ (rowo & 7);
                            *((_Float16*)((char*)&h0s[wr][0] + rowo * 128 + phys * 16 + (hc & 7) * 2)) = hv;
                        }
                    }
                }
            }
            if (xst) *(half8*)&xs[(p + 1) & 1][tid * 8] = xreg;
            __syncthreads();
        }
    } else {
        // ================= LAYER-1 WAVES =================
        const int hc = (wave - 4) * 16 + lr;

        half8 b1r[3][4][4];
#pragma unroll
        for (int kw = 0; kw < 3; ++kw)
#pragma unroll
        for (int kf = 0; kf < 4; ++kf)
#pragma unroll
        for (int cf = 0; cf < 4; ++cf)
            b1r[kw][kf][cf] = *(const half8*)&wt1[
                (size_t)(kw * 256 + cf * 64 + hc) * 128 + kf * 32 + kg * 8];

        float cbr1[4];
#pragma unroll
        for (int cf = 0; cf < 4; ++cf) cbr1[cf] = cb1[cf * 64 + hc];

        __syncthreads();   // init barrier

        for (int p = 0; p <= CST; ++p) {
            const int rd   = (p ^ 1) & 1;  // h0(t0+p-1) read; h1(t0+p-1) write
            const int h1rd = p & 1;        // h1(t0+p-2) read
            if (p >= 1) {
#pragma unroll
                for (int j = 0; j < 3; ++j) {
                    floatx4 acc[4];
#pragma unroll
                    for (int cf = 0; cf < 4; ++cf) acc[cf] = (floatx4)0.0f;
#pragma unroll
                    for (int kw = 0; kw < 3; ++kw)
#pragma unroll
                    for (int kf = 0; kf < 4; ++kf) {
                        int row = 16 * j + lr + kw;
                        half8 a;
                        if (kf < 2) {
                            int phys = (kf * 4 + kg) ^ (row & 7);
                            a = *(const half8*)&h0s[rd][row * 64 + phys * 8];
                        } else {
                            int phys = ((kf - 2) * 4 + kg) ^ (row & 7);
                            a = *(const half8*)&h1s[h1rd][row * 64 + phys * 8];
                        }
#pragma unroll
                        for (int cf = 0; cf < 4; ++cf)
                            acc[cf] = __builtin_amdgcn_mfma_f32_16x16x32_f16(a, b1r[kw][kf][cf], acc[cf], 0, 0, 0);
                    }
#pragma unroll
                    for (int r = 0; r < 4; ++r) {
                        int n = 16 * j + kg * 4 + r;
                        int cidx = n * 64 + (hc ^ (kg << 4));
                        float cv = c1s[cidx];
                        float cn = sigm(acc[1][r] + cbr1[1]) * cv
                                 + sigm(acc[0][r] + cbr1[0]) * tanh_fast(acc[3][r] + cbr1[3]);
                        c1s[cidx] = cn;
                        _Float16 hv = (_Float16)(sigm(acc[2][r] + cbr1[2]) * tanh_fast(cn));
                        int w = w0 - 6 + n;
                        if (w >= 0 && w < WIDTH) {
                            int rowo = n + 1;
                            int phys = (hc >> 3) ^ (rowo & 7);
                            *((_Float16*)((char*)&h1s[rd][0] + rowo * 128 + phys * 16 + (hc & 7) * 2)) = hv;
                        }
                        if (n >= CORE && n < CORE + 32)   // core: w in [w0, w0+32)
                            fcin[(size_t)b * FC1_IN + (size_t)((t0 + p - 1) * HID + hc) * WIDTH + w] = hv;
                    }
                }
            }
            __syncthreads();
        }
    }

    // ---- store core state for next chunk (h0/h1 final in buffer 0)
    if (save) {
        for (int i = tid; i < 32 * 64; i += 512) {
            int n = CORE + (i >> 6);
            int hc = i & 63;
            int w = w0 + (i >> 6);
            int rowo = n + 1;
            int physh = (hc >> 3) ^ (rowo & 7);
            h0g[((size_t)b * WIDTH + w) * 64 + hc] = h0s[0][rowo * 64 + physh * 8 + (hc & 7)];
            h1g[((size_t)b * WIDTH + w) * 64 + hc] = h1s[0][rowo * 64 + physh * 8 + (hc & 7)];
            int ci = n * 64 + (hc ^ (((n >> 2) & 3) << 4));
            c0g[((size_t)b * WIDTH + w) * 64 + hc] = c0s[ci];
            c1g[((size_t)b * WIDTH + w) * 64 + hc] = c1s[ci];
        }
    }
}

// ---------------- FC1 fp16 MFMA GEMM, K-split ----------------
#define KSLICE 1280
#define KPHASE 640
#define NSPLIT 256
#define ALDS_STRIDE 648

__global__ __launch_bounds__(512) void fc1_mfma(
    const _Float16* __restrict__ a,   // fcin [32][327680] fp16
    const float* __restrict__ w,      // fc1_w [512][327680] fp32
    float* __restrict__ part)         // [256][512][32] fp32 partials
{
    __shared__ _Float16 alds[32][ALDS_STRIDE];

    const int blk = blockIdx.x;
    const int tid = threadIdx.x;
    const int wv  = tid >> 6;
    const int ln  = tid & 63;
    const int lg  = ln >> 4;
    const int lr  = ln & 15;
    const int k0  = blk * KSLICE;

    floatx4 acc[2][4];
#pragma unroll
    for (int bt = 0; bt < 2; ++bt)
#pragma unroll
        for (int nt = 0; nt < 4; ++nt) acc[bt][nt] = (floatx4)0.0f;

    const float* wbase[4];
#pragma unroll
    for (int nt = 0; nt < 4; ++nt)
        wbase[nt] = w + (size_t)(wv * 64 + nt * 16 + lr) * FC1_IN + k0 + lg * 8;

    for (int p = 0; p < 2; ++p) {
        __syncthreads();
        for (int i = tid; i < 32 * 80; i += 512) {
            int r = i / 80;
            int c = (i - r * 80) * 8;
            *(half8*)&alds[r][c] =
                *(const half8*)&a[(size_t)r * FC1_IN + k0 + p * KPHASE + c];
        }
        __syncthreads();

        for (int kc = 0; kc < KPHASE / 32; ++kc) {
            half8 af0 = *(const half8*)&alds[lr][kc * 32 + lg * 8];
            half8 af1 = *(const half8*)&alds[16 + lr][kc * 32 + lg * 8];
#pragma unroll
            for (int nt = 0; nt < 4; ++nt) {
                const float* wp = wbase[nt] + p * KPHASE + kc * 32;
                float4 wlo = *(const float4*)wp;
                float4 whi = *(const float4*)(wp + 4);
                half8 bf;
                bf[0] = (_Float16)wlo.x; bf[1] = (_Float16)wlo.y;
                bf[2] = (_Float16)wlo.z; bf[3] = (_Float16)wlo.w;
                bf[4] = (_Float16)whi.x; bf[5] = (_Float16)whi.y;
                bf[6] = (_Float16)whi.z; bf[7] = (_Float16)whi.w;
                acc[0][nt] = __builtin_amdgcn_mfma_f32_16x16x32_f16(af0, bf, acc[0][nt], 0, 0, 0);
                acc[1][nt] = __builtin_amdgcn_mfma_f32_16x16x32_f16(af1, bf, acc[1][nt], 0, 0, 0);
            }
        }
    }

#pragma unroll
    for (int bt = 0; bt < 2; ++bt)
#pragma unroll
        for (int nt = 0; nt < 4; ++nt) {
            int n = wv * 64 + nt * 16 + lr;
            int b = bt * 16 + lg * 4;
            *(float4*)&part[((size_t)blk * FC1_OUT + n) * BATCH + b] =
                *(float4*)&acc[bt][nt];
        }
}

__global__ __launch_bounds__(256) void fc1_reduce(
    const float* __restrict__ part, const float* __restrict__ b1,
    float* __restrict__ z1)
{
    int e = blockIdx.x * 256 + threadIdx.x;  // e = n*32 + b
    float s = 0.0f;
    for (int ks = 0; ks < NSPLIT; ++ks)
        s += part[(size_t)ks * (FC1_OUT * BATCH) + e];
    int n = e >> 5, b = e & 31;
    float v = s + b1[n];
    z1[(size_t)b * FC1_OUT + n] = v > 0.0f ? v : 0.0f;
}

__global__ __launch_bounds__(128) void fc2_kernel(
    const float* __restrict__ z1, const float* __restrict__ w2,
    const float* __restrict__ b2, float* __restrict__ out)
{
    int t = threadIdx.x;
    if (t >= BATCH * OUT_DIM) return;
    int b = t / OUT_DIM, n = t - b * OUT_DIM;
    const float* zr = z1 + (size_t)b * FC1_OUT;
    const float* wr = w2 + (size_t)n * FC1_OUT;
    float acc = b2[n];
    for (int k = 0; k < FC1_OUT; ++k) acc += zr[k] * wr[k];
    if (n == 2) acc = sigm(acc);
    out[(size_t)b * OUT_DIM + n] = acc;
}

extern "C" void kernel_launch(void* const* d_in, const int* in_sizes, int n_in,
                              void* d_out, int out_size, void* d_ws, size_t ws_size,
                              hipStream_t stream) {
    const float* x   = (const float*)d_in[0];
    const float* cw0 = (const float*)d_in[1];
    const float* cb0 = (const float*)d_in[2];
    const float* cw1 = (const float*)d_in[3];
    const float* cb1 = (const float*)d_in[4];
    const float* w1  = (const float*)d_in[5];
    const float* b1  = (const float*)d_in[6];
    const float* w2  = (const float*)d_in[7];
    const float* b2  = (const float*)d_in[8];
    float* out = (float*)d_out;

    const size_t S = (size_t)BATCH * WIDTH * HID;   // 524288 elements
    char* p = (char*)d_ws;
    auto alloc = [&](size_t bytes) { char* r = p; p += (bytes + 255) & ~(size_t)255; return r; };

    _Float16* wt0  = (_Float16*)alloc((size_t)3 * 256 * 96 * 2);
    _Float16* wt1  = (_Float16*)alloc((size_t)3 * 256 * 128 * 2);
    _Float16* xT   = (_Float16*)alloc((size_t)TSTEPS * BATCH * WIDTH * 8 * 2);
    _Float16* fcin = (_Float16*)alloc((size_t)BATCH * FC1_IN * 2);
    _Float16* h0g  = (_Float16*)alloc(S * 2);
    _Float16* h1g  = (_Float16*)alloc(S * 2);
    float*    c0g  = (float*)alloc(S * 4);
    float*    c1g  = (float*)alloc(S * 4);
    float*    part = (float*)alloc((size_t)NSPLIT * FC1_OUT * BATCH * 4);
    float*    z1   = (float*)alloc((size_t)BATCH * FC1_OUT * 4);

    prep_w0<<<96, 256, 0, stream>>>(cw0, wt0);
    prep_w1<<<128, 256, 0, stream>>>(cw1, wt1);
    prep_x<<<(TSTEPS * BATCH * WIDTH + 255) / 256, 256, 0, stream>>>(x, xT);

    for (int k = 0; k < 4; ++k) {
        conv_chunk<<<dim3(BATCH, 8), 512, 0, stream>>>(
            xT, wt0, wt1, cb0, cb1, fcin, h0g, h1g, c0g, c1g,
            k * CST, (k == 0) ? 1 : 0, (k < 3) ? 1 : 0);
    }

    fc1_mfma<<<NSPLIT, 512, 0, stream>>>(fcin, w1, part);
    fc1_reduce<<<64, 256, 0, stream>>>(part, b1, z1);
    fc2_kernel<<<1, 128, 0, stream>>>(z1, w2, b2, out);
}

// Round 12
// 431.806 us; speedup vs baseline: 1.2603x; 1.0076x over previous
//
#include <hip/hip_runtime.h>
#include <hip/hip_bf16.h>
#include <cstddef>

// Problem constants
#define BATCH 32
#define TSTEPS 20
#define IN_DIM 3
#define WIDTH 256
#define HID 64
#define FC1_IN 327680   // HID * TSTEPS * WIDTH
#define FC1_OUT 512
#define OUT_DIM 3

// Conv time-chunking geometry
#define CST 5     // steps per chunk (4 chunks)
#define MARG 6    // halo margin >= CST+1
#define REGC 44   // region cols computed per block (32 core + 2*MARG)
#define CORE 6    // core starts at n=CORE
#define ROWS 50   // LDS slab rows (region rows 1..44, junk-absorb 45..48, zero 49)
#define CROWS 48  // c-state rows (junk rows 44..47 absorbed)

typedef _Float16 half8 __attribute__((ext_vector_type(8)));
typedef float floatx4 __attribute__((ext_vector_type(4)));

__device__ __forceinline__ float sigm(float x) {
    return 1.0f / (1.0f + __expf(-x));
}
__device__ __forceinline__ float tanh_fast(float x) {
    return 1.0f - 2.0f / (__expf(2.0f * x) + 1.0f);
}

// ---------------- prep kernels (once per launch) ----------------

// wt0[kw][co][cip=96]: cip 0..63 = h ch (orig ci 3+cip), 64..66 = x ch, 67..95 = 0.
__global__ __launch_bounds__(256) void prep_w0(
    const float* __restrict__ cw0, _Float16* __restrict__ wt0)
{
    int e = blockIdx.x * 256 + threadIdx.x;   // < 256*96
    if (e >= 256 * 96) return;
    int co = e / 96, cip = e - co * 96;
    int ci = (cip < 64) ? (3 + cip) : (cip < 67 ? cip - 64 : -1);
    float v[3] = {0.f, 0.f, 0.f};
    if (ci >= 0) {
#pragma unroll
        for (int kw = 0; kw < 3; ++kw)
            v[kw] = cw0[(size_t)(co * 67 + ci) * 9 + 3 + kw];
    }
#pragma unroll
    for (int kw = 0; kw < 3; ++kw)
        wt0[(size_t)(kw * 256 + co) * 96 + cip] = (_Float16)v[kw];
}

// wt1[kw][co][ci=128]: direct (z = [h0 64 | h1 64] matches cw1 ci order).
__global__ __launch_bounds__(256) void prep_w1(
    const float* __restrict__ cw1, _Float16* __restrict__ wt1)
{
    int e = blockIdx.x * 256 + threadIdx.x;   // < 256*128
    int co = e >> 7, ci = e & 127;
#pragma unroll
    for (int kw = 0; kw < 3; ++kw)
        wt1[(size_t)(kw * 256 + co) * 128 + ci] =
            (_Float16)cw1[(size_t)(co * 128 + ci) * 9 + 3 + kw];
}

// xT[t][b][w][8] fp16: ch 0..2 from x[b][t][ch][w], 3..7 = 0.
__global__ __launch_bounds__(256) void prep_x(
    const float* __restrict__ x, _Float16* __restrict__ xT)
{
    int e = blockIdx.x * 256 + threadIdx.x;   // < 20*32*256
    if (e >= TSTEPS * BATCH * WIDTH) return;
    int t = e / (BATCH * WIDTH);
    int rem = e - t * BATCH * WIDTH;
    int b = rem >> 8, w = rem & 255;
    half8 v = {};
#pragma unroll
    for (int ci = 0; ci < 3; ++ci)
        v[ci] = (_Float16)x[(size_t)((b * TSTEPS + t) * IN_DIM + ci) * WIDTH + w];
    *(half8*)&xT[(size_t)e * 8] = v;
}

// ---------------- time-chunked ConvLSTM kernel (5 steps/launch) ----------
// Grid (32 b, 8 wtiles), 512 threads = 8 waves; waves 0-3 = layer0, 4-7 = layer1.
// Per chunk each block computes region w in [w0-6, w0+38) (44 cols); boundary
// contamination grows 1 col/layer/step, margin 6 >= 5+1 keeps core [w0,w0+32)
// exact. Kernel boundary = exact halo exchange. Row s <-> w = w0-7+s.
// 6 phases/chunk: phase p runs L0(t0+p) || L1(t0+p-1). Weights register-
// resident; h0/h1 double-buffered LDS; c0/c1 LDS. setprio(1) around MFMA
// clusters (T5: wave role-split present -> scheduler can arbitrate).
__global__ __launch_bounds__(512) void conv_chunk(
    const _Float16* __restrict__ xT,   // [t][b][w][8]
    const _Float16* __restrict__ wt0,  // [3][256][96]  (reordered slots)
    const _Float16* __restrict__ wt1,  // [3][256][128]
    const float* __restrict__ cb0,
    const float* __restrict__ cb1,
    _Float16* __restrict__ fcin,       // [b][(t*64+hc)*256+w] fp16
    _Float16* __restrict__ h0g,        // [b][w][64] state between chunks
    _Float16* __restrict__ h1g,
    float* __restrict__ c0g,
    float* __restrict__ c1g,
    int t0, int first, int save)
{
    __shared__ __align__(16) _Float16 h0s[2][ROWS * 64];
    __shared__ __align__(16) _Float16 h1s[2][ROWS * 64];
    __shared__ __align__(16) _Float16 xs[2][ROWS * 8];
    __shared__ float c0s[CROWS * 64];   // idx n*64 + (hc ^ (owner_kg<<4))
    __shared__ float c1s[CROWS * 64];
    __shared__ __align__(16) _Float16 zero16[8];

    const int b    = blockIdx.x;
    const int w0   = blockIdx.y * 32;
    const int tid  = threadIdx.x;
    const int wave = tid >> 6;
    const int ln = tid & 63;
    const int lr = ln & 15;
    const int kg = ln >> 4;

    // ---- zero-init LDS
    {
        _Float16* h0f = &h0s[0][0];
        _Float16* h1f = &h1s[0][0];
        for (int i = tid; i < 2 * ROWS * 64; i += 512) { h0f[i] = (_Float16)0.0f; h1f[i] = (_Float16)0.0f; }
        for (int i = tid; i < CROWS * 64; i += 512) { c0s[i] = 0.0f; c1s[i] = 0.0f; }
        for (int i = tid; i < ROWS * 8; i += 512) xs[1][i] = (_Float16)0.0f;
        if (tid < 8) zero16[tid] = (_Float16)0.0f;
    }
    __syncthreads();

    // ---- stage x(t0) + load chunk-start state
    {
        if (tid < ROWS) {
            int w = w0 - 7 + tid;
            half8 v = {};
            if (w >= 0 && w < WIDTH)
                v = *(const half8*)&xT[((size_t)(t0 * BATCH + b) * WIDTH + w) * 8];
            *(half8*)&xs[0][tid * 8] = v;
        }
        if (!first) {
            for (int i = tid; i < REGC * 8; i += 512) {
                int row = 1 + (i >> 3), c = i & 7;
                int w = w0 - 7 + row;
                half8 v0 = {}, v1 = {};
                if (w >= 0 && w < WIDTH) {
                    v0 = *(const half8*)&h0g[((size_t)b * WIDTH + w) * 64 + c * 8];
                    v1 = *(const half8*)&h1g[((size_t)b * WIDTH + w) * 64 + c * 8];
                }
                int phys = c ^ (row & 7);
                *(half8*)&h0s[1][row * 64 + phys * 8] = v0;
                *(half8*)&h1s[1][row * 64 + phys * 8] = v1;
            }
            for (int i = tid; i < REGC * 64; i += 512) {
                int n = i >> 6, hc = i & 63;
                int w = w0 - 6 + n;
                float v0 = 0.f, v1 = 0.f;
                if (w >= 0 && w < WIDTH) {
                    v0 = c0g[((size_t)b * WIDTH + w) * 64 + hc];
                    v1 = c1g[((size_t)b * WIDTH + w) * 64 + hc];
                }
                int ci = n * 64 + (hc ^ (((n >> 2) & 3) << 4));
                c0s[ci] = v0;
                c1s[ci] = v1;
            }
        }
    }

    if (wave < 4) {
        // ================= LAYER-0 WAVES =================
        const int hc = wave * 16 + lr;

        half8 b0r[3][3][4];
#pragma unroll
        for (int kw = 0; kw < 3; ++kw)
#pragma unroll
        for (int kf = 0; kf < 3; ++kf)
#pragma unroll
        for (int cf = 0; cf < 4; ++cf)
            b0r[kw][kf][cf] = *(const half8*)&wt0[
                (size_t)(kw * 256 + cf * 64 + hc) * 96 + kf * 32 + kg * 8];

        float cbr0[4];
#pragma unroll
        for (int cf = 0; cf < 4; ++cf) cbr0[cf] = cb0[cf * 64 + hc];

        __syncthreads();   // init barrier

        for (int p = 0; p <= CST; ++p) {
            const int rd = (p ^ 1) & 1;   // h0(t0+p-1)
            const int wr = p & 1;         // h0(t0+p) dest; xs[p&1] = x(t0+p)
            half8 xreg = {};
            const bool xst = (p < CST - 1) && (tid < ROWS);
            if (xst) {
                int w = w0 - 7 + tid;
                if (w >= 0 && w < WIDTH)
                    xreg = *(const half8*)&xT[((size_t)((t0 + p + 1) * BATCH + b) * WIDTH + w) * 8];
            }
            if (p < CST) {
#pragma unroll
                for (int j = 0; j < 3; ++j) {
                    floatx4 acc[4];
#pragma unroll
                    for (int cf = 0; cf < 4; ++cf) acc[cf] = (floatx4)0.0f;
                    __builtin_amdgcn_s_setprio(1);
#pragma unroll
                    for (int kw = 0; kw < 3; ++kw)
#pragma unroll
                    for (int kf = 0; kf < 3; ++kf) {
                        int row = 16 * j + lr + kw;     // <= 49
                        half8 a;
                        if (kf < 2) {
                            int phys = (kf * 4 + kg) ^ (row & 7);
                            a = *(const half8*)&h0s[rd][row * 64 + phys * 8];
                        } else {
                            a = (kg == 0) ? *(const half8*)&xs[wr][row * 8]
                                          : *(const half8*)&zero16[0];
                        }
#pragma unroll
                        for (int cf = 0; cf < 4; ++cf)
                            acc[cf] = __builtin_amdgcn_mfma_f32_16x16x32_f16(a, b0r[kw][kf][cf], acc[cf], 0, 0, 0);
                    }
                    __builtin_amdgcn_s_setprio(0);
#pragma unroll
                    for (int r = 0; r < 4; ++r) {
                        int n = 16 * j + kg * 4 + r;   // 0..47 (44..47 junk, absorbed)
                        int cidx = n * 64 + (hc ^ (kg << 4));
                        float cv = c0s[cidx];
                        float cn = sigm(acc[1][r] + cbr0[1]) * cv
                                 + sigm(acc[0][r] + cbr0[0]) * tanh_fast(acc[3][r] + cbr0[3]);
                        c0s[cidx] = cn;
                        int w = w0 - 6 + n;
                        if (w >= 0 && w < WIDTH) {   // domain zero-pad preserved
                            _Float16 hv = (_Float16)(sigm(acc[2][r] + cbr0[2]) * tanh_fast(cn));
                            int rowo = n + 1;        // <= 48 < ROWS
                            int phys = (hc >> 3) ^ (rowo & 7);
                            *((_Float16*)((char*)&h0s[wr][0] + rowo * 128 + phys * 16 + (hc & 7) * 2)) = hv;
                        }
                    }
                }
            }
            if (xst) *(half8*)&xs[(p + 1) & 1][tid * 8] = xreg;
            __syncthreads();
        }
    } else {
        // ================= LAYER-1 WAVES =================
        const int hc = (wave - 4) * 16 + lr;

        half8 b1r[3][4][4];
#pragma unroll
        for (int kw = 0; kw < 3; ++kw)
#pragma unroll
        for (int kf = 0; kf < 4; ++kf)
#pragma unroll
        for (int cf = 0; cf < 4; ++cf)
            b1r[kw][kf][cf] = *(const half8*)&wt1[
                (size_t)(kw * 256 + cf * 64 + hc) * 128 + kf * 32 + kg * 8];

        float cbr1[4];
#pragma unroll
        for (int cf = 0; cf < 4; ++cf) cbr1[cf] = cb1[cf * 64 + hc];

        __syncthreads();   // init barrier

        for (int p = 0; p <= CST; ++p) {
            const int rd   = (p ^ 1) & 1;  // h0(t0+p-1) read; h1(t0+p-1) write
            const int h1rd = p & 1;        // h1(t0+p-2) read
            if (p >= 1) {
#pragma unroll
                for (int j = 0; j < 3; ++j) {
                    floatx4 acc[4];
#pragma unroll
                    for (int cf = 0; cf < 4; ++cf) acc[cf] = (floatx4)0.0f;
                    __builtin_amdgcn_s_setprio(1);
#pragma unroll
                    for (int kw = 0; kw < 3; ++kw)
#pragma unroll
                    for (int kf = 0; kf < 4; ++kf) {
                        int row = 16 * j + lr + kw;
                        half8 a;
                        if (kf < 2) {
                            int phys = (kf * 4 + kg) ^ (row & 7);
                            a = *(const half8*)&h0s[rd][row * 64 + phys * 8];
                        } else {
                            int phys = ((kf - 2) * 4 + kg) ^ (row & 7);
                            a = *(const half8*)&h1s[h1rd][row * 64 + phys * 8];
                        }
#pragma unroll
                        for (int cf = 0; cf < 4; ++cf)
                            acc[cf] = __builtin_amdgcn_mfma_f32_16x16x32_f16(a, b1r[kw][kf][cf], acc[cf], 0, 0, 0);
                    }
                    __builtin_amdgcn_s_setprio(0);
#pragma unroll
                    for (int r = 0; r < 4; ++r) {
                        int n = 16 * j + kg * 4 + r;
                        int cidx = n * 64 + (hc ^ (kg << 4));
                        float cv = c1s[cidx];
                        float cn = sigm(acc[1][r] + cbr1[1]) * cv
                                 + sigm(acc[0][r] + cbr1[0]) * tanh_fast(acc[3][r] + cbr1[3]);
                        c1s[cidx] = cn;
                        _Float16 hv = (_Float16)(sigm(acc[2][r] + cbr1[2]) * tanh_fast(cn));
                        int w = w0 - 6 + n;
                        if (w >= 0 && w < WIDTH) {
                            int rowo = n + 1;
                            int phys = (hc >> 3) ^ (rowo & 7);
                            *((_Float16*)((char*)&h1s[rd][0] + rowo * 128 + phys * 16 + (hc & 7) * 2)) = hv;
                        }
                        if (n >= CORE && n < CORE + 32)   // core: w in [w0, w0+32)
                            fcin[(size_t)b * FC1_IN + (size_t)((t0 + p - 1) * HID + hc) * WIDTH + w] = hv;
                    }
                }
            }
            __syncthreads();
        }
    }

    // ---- store core state for next chunk (h0/h1 final in buffer 0)
    if (save) {
        for (int i = tid; i < 32 * 64; i += 512) {
            int n = CORE + (i >> 6);
            int hc = i & 63;
            int w = w0 + (i >> 6);
            int rowo = n + 1;
            int physh = (hc >> 3) ^ (rowo & 7);
            h0g[((size_t)b * WIDTH + w) * 64 + hc] = h0s[0][rowo * 64 + physh * 8 + (hc & 7)];
            h1g[((size_t)b * WIDTH + w) * 64 + hc] = h1s[0][rowo * 64 + physh * 8 + (hc & 7)];
            int ci = n * 64 + (hc ^ (((n >> 2) & 3) << 4));
            c0g[((size_t)b * WIDTH + w) * 64 + hc] = c0s[ci];
            c1g[((size_t)b * WIDTH + w) * 64 + hc] = c1s[ci];
        }
    }
}

// ---------------- FC1 fp16 MFMA GEMM, K-split, 16 waves/block ------------
#define KSLICE 1280
#define KPHASE 640
#define NSPLIT 256
#define ALDS_STRIDE 648

__global__ __launch_bounds__(1024) void fc1_mfma(
    const _Float16* __restrict__ a,   // fcin [32][327680] fp16
    const float* __restrict__ w,      // fc1_w [512][327680] fp32
    float* __restrict__ part)         // [256][512][32] fp32 partials
{
    __shared__ _Float16 alds[32][ALDS_STRIDE];

    const int blk = blockIdx.x;
    const int tid = threadIdx.x;
    const int wv  = tid >> 6;         // 0..15, each owns 32 n
    const int ln  = tid & 63;
    const int lg  = ln >> 4;
    const int lr  = ln & 15;
    const int k0  = blk * KSLICE;

    floatx4 acc[2][2];
#pragma unroll
    for (int bt = 0; bt < 2; ++bt)
#pragma unroll
        for (int nt = 0; nt < 2; ++nt) acc[bt][nt] = (floatx4)0.0f;

    const float* wbase[2];
#pragma unroll
    for (int nt = 0; nt < 2; ++nt)
        wbase[nt] = w + (size_t)(wv * 32 + nt * 16 + lr) * FC1_IN + k0 + lg * 8;

    for (int p = 0; p < 2; ++p) {
        __syncthreads();
        for (int i = tid; i < 32 * 80; i += 1024) {
            int r = i / 80;
            int c = (i - r * 80) * 8;
            *(half8*)&alds[r][c] =
                *(const half8*)&a[(size_t)r * FC1_IN + k0 + p * KPHASE + c];
        }
        __syncthreads();

        for (int kc = 0; kc < KPHASE / 32; ++kc) {
            half8 af0 = *(const half8*)&alds[lr][kc * 32 + lg * 8];
            half8 af1 = *(const half8*)&alds[16 + lr][kc * 32 + lg * 8];
#pragma unroll
            for (int nt = 0; nt < 2; ++nt) {
                const float* wp = wbase[nt] + p * KPHASE + kc * 32;
                float4 wlo = *(const float4*)wp;
                float4 whi = *(const float4*)(wp + 4);
                half8 bf;
                bf[0] = (_Float16)wlo.x; bf[1] = (_Float16)wlo.y;
                bf[2] = (_Float16)wlo.z; bf[3] = (_Float16)wlo.w;
                bf[4] = (_Float16)whi.x; bf[5] = (_Float16)whi.y;
                bf[6] = (_Float16)whi.z; bf[7] = (_Float16)whi.w;
                acc[0][nt] = __builtin_amdgcn_mfma_f32_16x16x32_f16(af0, bf, acc[0][nt], 0, 0, 0);
                acc[1][nt] = __builtin_amdgcn_mfma_f32_16x16x32_f16(af1, bf, acc[1][nt], 0, 0, 0);
            }
        }
    }

#pragma unroll
    for (int bt = 0; bt < 2; ++bt)
#pragma unroll
        for (int nt = 0; nt < 2; ++nt) {
            int n = wv * 32 + nt * 16 + lr;
            int b = bt * 16 + lg * 4;
            *(float4*)&part[((size_t)blk * FC1_OUT + n) * BATCH + b] =
                *(float4*)&acc[bt][nt];
        }
}

__global__ __launch_bounds__(256) void fc1_reduce(
    const float* __restrict__ part, const float* __restrict__ b1,
    float* __restrict__ z1)
{
    int e = blockIdx.x * 256 + threadIdx.x;  // e = n*32 + b
    float s = 0.0f;
    for (int ks = 0; ks < NSPLIT; ++ks)
        s += part[(size_t)ks * (FC1_OUT * BATCH) + e];
    int n = e >> 5, b = e & 31;
    float v = s + b1[n];
    z1[(size_t)b * FC1_OUT + n] = v > 0.0f ? v : 0.0f;
}

__global__ __launch_bounds__(128) void fc2_kernel(
    const float* __restrict__ z1, const float* __restrict__ w2,
    const float* __restrict__ b2, float* __restrict__ out)
{
    int t = threadIdx.x;
    if (t >= BATCH * OUT_DIM) return;
    int b = t / OUT_DIM, n = t - b * OUT_DIM;
    const float* zr = z1 + (size_t)b * FC1_OUT;
    const float* wr = w2 + (size_t)n * FC1_OUT;
    float acc = b2[n];
    for (int k = 0; k < FC1_OUT; ++k) acc += zr[k] * wr[k];
    if (n == 2) acc = sigm(acc);
    out[(size_t)b * OUT_DIM + n] = acc;
}

extern "C" void kernel_launch(void* const* d_in, const int* in_sizes, int n_in,
                              void* d_out, int out_size, void* d_ws, size_t ws_size,
                              hipStream_t stream) {
    const float* x   = (const float*)d_in[0];
    const float* cw0 = (const float*)d_in[1];
    const float* cb0 = (const float*)d_in[2];
    const float* cw1 = (const float*)d_in[3];
    const float* cb1 = (const float*)d_in[4];
    const float* w1  = (const float*)d_in[5];
    const float* b1  = (const float*)d_in[6];
    const float* w2  = (const float*)d_in[7];
    const float* b2  = (const float*)d_in[8];
    float* out = (float*)d_out;

    const size_t S = (size_t)BATCH * WIDTH * HID;   // 524288 elements
    char* p = (char*)d_ws;
    auto alloc = [&](size_t bytes) { char* r = p; p += (bytes + 255) & ~(size_t)255; return r; };

    _Float16* wt0  = (_Float16*)alloc((size_t)3 * 256 * 96 * 2);
    _Float16* wt1  = (_Float16*)alloc((size_t)3 * 256 * 128 * 2);
    _Float16* xT   = (_Float16*)alloc((size_t)TSTEPS * BATCH * WIDTH * 8 * 2);
    _Float16* fcin = (_Float16*)alloc((size_t)BATCH * FC1_IN * 2);
    _Float16* h0g  = (_Float16*)alloc(S * 2);
    _Float16* h1g  = (_Float16*)alloc(S * 2);
    float*    c0g  = (float*)alloc(S * 4);
    float*    c1g  = (float*)alloc(S * 4);
    float*    part = (float*)alloc((size_t)NSPLIT * FC1_OUT * BATCH * 4);
    float*    z1   = (float*)alloc((size_t)BATCH * FC1_OUT * 4);

    prep_w0<<<96, 256, 0, stream>>>(cw0, wt0);
    prep_w1<<<128, 256, 0, stream>>>(cw1, wt1);
    prep_x<<<(TSTEPS * BATCH * WIDTH + 255) / 256, 256, 0, stream>>>(x, xT);

    for (int k = 0; k < 4; ++k) {
        conv_chunk<<<dim3(BATCH, 8), 512, 0, stream>>>(
            xT, wt0, wt1, cb0, cb1, fcin, h0g, h1g, c0g, c1g,
            k * CST, (k == 0) ? 1 : 0, (k < 3) ? 1 : 0);
    }

    fc1_mfma<<<NSPLIT, 1024, 0, stream>>>(fcin, w1, part);
    fc1_reduce<<<64, 256, 0, stream>>>(part, b1, z1);
    fc2_kernel<<<1, 128, 0, stream>>>(z1, w2, b2, out);
}